// Round 3
// baseline (749.916 us; speedup 1.0000x reference)
//
#include <hip/hip_runtime.h>
#include <math.h>

// ---------------------------------------------------------------------------
// FraudDetectionGCN: 3x GCNConv(relu) + FC + log_softmax, fp32 throughout.
// R3 change vs R2:
//  * lin kernels were GRID-LIMITED (1024 blocks = 16 waves/CU = 38% occupancy,
//    VALUBusy 14%, latency-bound). Now grid = ceil(N/16), one 4-row group per
//    wave, no loop -> 8 waves/SIMD of latency hiding.
// norm factorization: out[n] = dinv[n]*(sum_{s->n} g[s] + g[n]) + b,
// where g = dinv[:,None] * (h @ W).
// ---------------------------------------------------------------------------

static inline size_t alignup(size_t x){ return (x + 511) & ~size_t(511); }

#define NBUCK 1024          // histogram bins (dst>>7), NB=ceil(N/128) used
#define CHUNK 8192          // edges per block in hist/scatter
#define CCAP  3584          // max edges per bucket (mean ~2046, +30 sigma)

__global__ void zero_kernel(int* __restrict__ p, int n){
  int i = blockIdx.x*256 + threadIdx.x;
  if(i<n) p[i] = 0;
}

// WT[j*K + k] = W[k*64 + j] for all three layer weights (one launch).
__global__ void transpose_w_kernel(const float* __restrict__ W1, const float* __restrict__ W2,
                                   const float* __restrict__ W3, float* __restrict__ WT1,
                                   float* __restrict__ WT2, float* __restrict__ WT3){
  int i = blockIdx.x*256 + threadIdx.x;
  if(i < 128*64){ int k=i>>6, j=i&63; WT1[j*128+k] = W1[i]; }
  else if(i < 128*64+64*64){ int m=i-128*64; int k=m>>6, j=m&63; WT2[j*64+k]=W2[m]; }
  else if(i < 128*64+2*64*64){ int m=i-128*64-64*64; int k=m>>6, j=m&63; WT3[j*64+k]=W3[m]; }
}

// Pass A: global histogram of dst>>7 (LDS-aggregated).
__global__ __launch_bounds__(256) void hist_kernel(const int* __restrict__ dst,
                                                   int* __restrict__ bcnt, int E){
  __shared__ int h[NBUCK];
  int t = threadIdx.x;
  for(int i=t;i<NBUCK;i+=256) h[i]=0;
  __syncthreads();
  int base = blockIdx.x*CHUNK;
  #pragma unroll 4
  for(int i=0;i<CHUNK;i+=256){
    int e = base+i+t;
    if(e<E) atomicAdd(&h[dst[e]>>7], 1);
  }
  __syncthreads();
  for(int i=t;i<NBUCK;i+=256) if(h[i]) atomicAdd(&bcnt[i], h[i]);
}

// Exclusive scan of 1024 bucket counts (single block). bbase = bfill = prefix.
__global__ void scan_buckets_kernel(const int* __restrict__ bcnt, int* __restrict__ bbase,
                                    int* __restrict__ bfill){
  __shared__ int sh[256];
  int t = threadIdx.x;
  int v0=bcnt[4*t], v1=bcnt[4*t+1], v2=bcnt[4*t+2], v3=bcnt[4*t+3];
  int ts = v0+v1+v2+v3;
  sh[t]=ts; __syncthreads();
  for(int off=1; off<256; off<<=1){
    int x=(t>=off)?sh[t-off]:0; __syncthreads();
    sh[t]+=x; __syncthreads();
  }
  int run = sh[t]-ts;
  int i0=4*t;
  bbase[i0+0]=run; bfill[i0+0]=run; run+=v0;
  bbase[i0+1]=run; bfill[i0+1]=run; run+=v1;
  bbase[i0+2]=run; bfill[i0+2]=run; run+=v2;
  bbase[i0+3]=run; bfill[i0+3]=run;
}

// Pass B: scatter packed (local_dst<<17 | src) into bucket regions.
// Each block reserves per-bucket ranges with ONE global atomic per bucket,
// then fills them via LDS slot counters -> ~sequential writes per bucket.
__global__ __launch_bounds__(256) void scatter_kernel(const int* __restrict__ src,
                                                      const int* __restrict__ dst,
                                                      int* __restrict__ bfill,
                                                      int* __restrict__ pairs, int E){
  __shared__ int h[NBUCK];
  __shared__ int base[NBUCK];
  int t = threadIdx.x;
  for(int i=t;i<NBUCK;i+=256) h[i]=0;
  __syncthreads();
  int cbase = blockIdx.x*CHUNK;
  int d[CHUNK/256];
  #pragma unroll
  for(int i=0;i<CHUNK/256;i++){
    int e = cbase+i*256+t;
    d[i] = (e<E) ? dst[e] : -1;
    if(d[i]>=0) atomicAdd(&h[d[i]>>7], 1);
  }
  __syncthreads();
  for(int i=t;i<NBUCK;i+=256) base[i] = h[i] ? atomicAdd(&bfill[i], h[i]) : 0;
  __syncthreads();
  #pragma unroll
  for(int i=0;i<CHUNK/256;i++){
    int e = cbase+i*256+t;
    if(d[i]>=0){
      int b = d[i]>>7;
      int slot = atomicAdd(&base[b], 1);
      pairs[slot] = ((d[i]&127)<<17) | src[e];
    }
  }
}

// Pass C: one block per bucket (128 dst nodes). LDS counting sort ->
// row_ptr, dinv, and fully-sequential col writes.
__global__ __launch_bounds__(256) void bucket_csr_kernel(const int* __restrict__ pairs,
                                                         const int* __restrict__ bbase,
                                                         int* __restrict__ row_ptr,
                                                         float* __restrict__ dinv,
                                                         int* __restrict__ col,
                                                         int N, int E){
  __shared__ int hist[128];
  __shared__ int pref[128];
  __shared__ int fill[128];
  __shared__ int srcs[CCAP];
  int b = blockIdx.x, t = threadIdx.x;
  int s = bbase[b], e = bbase[b+1];
  int cnt = e - s; if(cnt > CCAP) cnt = CCAP;   // unreachable guard
  if(t<128) hist[t]=0;
  __syncthreads();
  int v[CCAP/256];
  #pragma unroll
  for(int i=0;i<CCAP/256;i++){
    int idx = i*256 + t;
    if(idx<cnt){ v[i]=pairs[s+idx]; atomicAdd(&hist[v[i]>>17], 1); }
  }
  __syncthreads();
  if(t<128) pref[t]=hist[t];
  __syncthreads();
  for(int off=1; off<128; off<<=1){
    int x=0;
    if(t<128 && t>=off) x=pref[t-off];
    __syncthreads();
    if(t<128) pref[t]+=x;
    __syncthreads();
  }
  if(t<128){
    int ex = pref[t]-hist[t];                 // exclusive prefix
    fill[t]=ex;
    int node = b*128 + t;
    if(node<N){
      row_ptr[node] = s + ex;
      dinv[node] = rsqrtf((float)(hist[t]+1)); // +1 self loop
    }
  }
  if(b==0 && t==0) row_ptr[N]=E;
  __syncthreads();
  #pragma unroll
  for(int i=0;i<CCAP/256;i++){
    int idx = i*256 + t;
    if(idx<cnt){
      int ld = v[i]>>17;
      int pos = atomicAdd(&fill[ld], 1);
      srcs[pos] = v[i] & 0x1FFFF;
    }
  }
  __syncthreads();
  for(int i=t;i<cnt;i+=256) col[s+i]=srcs[i];
}

// g[n,:] = dinv[n] * (h[n,:K] @ W[K,64]).  WT[j*K+k] read from global
// (L1-resident, coalesced float4). One 4-row group per wave, one pass —
// grid = ceil(N/16) so occupancy is wave-capacity-limited, not grid-limited.
template<int K>
__global__ __launch_bounds__(256) void lin_kernel(const float* __restrict__ h,
                                                  const float* __restrict__ WT,
                                                  const float* __restrict__ dinv,
                                                  float* __restrict__ g, int N){
  int t = threadIdx.x, wave = t>>6, lane = t&63;
  const float* wrow = &WT[lane*K];
  int base = (blockIdx.x*4+wave)*4;
  if(base>=N) return;
  bool v1 = base+1<N, v2 = base+2<N, v3 = base+3<N;
  const float* h0 = &h[(size_t)base*K];
  const float* h1 = v1 ? &h[(size_t)(base+1)*K] : h0;
  const float* h2 = v2 ? &h[(size_t)(base+2)*K] : h0;
  const float* h3 = v3 ? &h[(size_t)(base+3)*K] : h0;
  float a0=0.f, a1=0.f, a2=0.f, a3=0.f;
  #pragma unroll 8
  for(int k=0; k<K; k+=4){
    float4 w4 = *(const float4*)&wrow[k];
    float4 x0 = *(const float4*)&h0[k];
    float4 x1 = *(const float4*)&h1[k];
    float4 x2 = *(const float4*)&h2[k];
    float4 x3 = *(const float4*)&h3[k];
    a0 += x0.x*w4.x + x0.y*w4.y + x0.z*w4.z + x0.w*w4.w;
    a1 += x1.x*w4.x + x1.y*w4.y + x1.z*w4.z + x1.w*w4.w;
    a2 += x2.x*w4.x + x2.y*w4.y + x2.z*w4.z + x2.w*w4.w;
    a3 += x3.x*w4.x + x3.y*w4.y + x3.z*w4.z + x3.w*w4.w;
  }
  g[(size_t)base*64+lane] = dinv[base]*a0;
  if(v1) g[(size_t)(base+1)*64+lane] = dinv[base+1]*a1;
  if(v2) g[(size_t)(base+2)*64+lane] = dinv[base+2]*a2;
  if(v3) g[(size_t)(base+3)*64+lane] = dinv[base+3]*a3;
}

// h[n,:] = relu(dinv[n]*(g[n,:] + sum_{CSR} g[col,:]) + bias). One wave/node,
// lane == feature; 8-deep unroll for outstanding 256B row gathers.
__global__ __launch_bounds__(256) void agg_kernel(const float* __restrict__ g,
                                                  const int* __restrict__ row_ptr,
                                                  const int* __restrict__ col,
                                                  const float* __restrict__ dinv,
                                                  const float* __restrict__ bias,
                                                  float* __restrict__ h, int N){
  int wave = threadIdx.x>>6, lane = threadIdx.x&63;
  int n = blockIdx.x*4 + wave;
  if(n>=N) return;
  int s = row_ptr[n], e = row_ptr[n+1];
  float acc = g[(size_t)n*64 + lane];          // self loop
  int i = s;
  for(; i+8<=e; i+=8){
    int c0=col[i],c1=col[i+1],c2=col[i+2],c3=col[i+3];
    int c4=col[i+4],c5=col[i+5],c6=col[i+6],c7=col[i+7];
    float x0=g[(size_t)c0*64+lane], x1=g[(size_t)c1*64+lane];
    float x2=g[(size_t)c2*64+lane], x3=g[(size_t)c3*64+lane];
    float x4=g[(size_t)c4*64+lane], x5=g[(size_t)c5*64+lane];
    float x6=g[(size_t)c6*64+lane], x7=g[(size_t)c7*64+lane];
    acc += ((x0+x1)+(x2+x3)) + ((x4+x5)+(x6+x7));
  }
  for(; i<e; ++i) acc += g[(size_t)col[i]*64 + lane];
  float r = dinv[n]*acc + bias[lane];
  h[(size_t)n*64 + lane] = fmaxf(r, 0.0f);
}

// logits = h3 @ Wfc[64,2] + bfc; out = log_softmax over C=2.
__global__ __launch_bounds__(256) void final_kernel(const float* __restrict__ h,
                                                    const float* __restrict__ Wfc,
                                                    const float* __restrict__ bfc,
                                                    float* __restrict__ out, int N){
  int wave = threadIdx.x>>6, lane = threadIdx.x&63;
  int n = blockIdx.x*4 + wave;
  if(n>=N) return;
  float hv = h[(size_t)n*64 + lane];
  float2 w = *(const float2*)&Wfc[lane*2];
  float p0 = hv*w.x, p1 = hv*w.y;
  for(int off=32; off; off>>=1){
    p0 += __shfl_down(p0, off);
    p1 += __shfl_down(p1, off);
  }
  if(lane==0){
    float l0 = p0 + bfc[0], l1 = p1 + bfc[1];
    float m  = fmaxf(l0, l1);
    float lse = m + logf(expf(l0-m) + expf(l1-m));
    out[(size_t)n*2+0] = l0 - lse;
    out[(size_t)n*2+1] = l1 - lse;
  }
}

extern "C" void kernel_launch(void* const* d_in, const int* in_sizes, int n_in,
                              void* d_out, int out_size, void* d_ws, size_t ws_size,
                              hipStream_t stream) {
  (void)n_in; (void)out_size; (void)ws_size;
  const float* x   = (const float*)d_in[0];
  const int*   ei  = (const int*)  d_in[1];
  const float* W1  = (const float*)d_in[2];
  const float* b1  = (const float*)d_in[3];
  const float* W2  = (const float*)d_in[4];
  const float* b2  = (const float*)d_in[5];
  const float* W3  = (const float*)d_in[6];
  const float* b3  = (const float*)d_in[7];
  const float* Wfc = (const float*)d_in[8];
  const float* bfc = (const float*)d_in[9];
  float* out = (float*)d_out;

  const int N = in_sizes[0] / 128;   // 100000
  const int E = in_sizes[1] / 2;     // 1600000
  const int* src = ei;
  const int* dst = ei + E;
  const int NB = (N + 127) / 128;    // 782 buckets

  // ---- workspace carve ----
  char* w = (char*)d_ws;
  float* WT1     = (float*)w; w += alignup((size_t)64*128*4);
  float* WT2     = (float*)w; w += alignup((size_t)64*64*4);
  float* WT3     = (float*)w; w += alignup((size_t)64*64*4);
  int*   bcnt    = (int*)  w; w += alignup((size_t)NBUCK*4);
  int*   bbase   = (int*)  w; w += alignup((size_t)(NBUCK+1)*4);
  int*   bfill   = (int*)  w; w += alignup((size_t)NBUCK*4);
  int*   pairs   = (int*)  w; w += alignup((size_t)E*4);
  int*   row_ptr = (int*)  w; w += alignup((size_t)(N+1)*4);
  float* dinv    = (float*)w; w += alignup((size_t)N*4);
  int*   col     = (int*)  w; w += alignup((size_t)E*4);
  float* bufA    = (float*)w; w += alignup((size_t)N*64*4);
  float* bufB    = (float*)w; w += alignup((size_t)N*64*4);

  const int nblkE = (E + CHUNK - 1) / CHUNK;   // 196
  const int nblkLin = (N + 15) / 16;           // 6250: 4 rows/wave, 4 waves/blk

  // ---- CSR build ----
  zero_kernel<<<(NBUCK+255)/256, 256, 0, stream>>>(bcnt, NBUCK);
  transpose_w_kernel<<<64, 256, 0, stream>>>(W1, W2, W3, WT1, WT2, WT3);
  hist_kernel<<<nblkE, 256, 0, stream>>>(dst, bcnt, E);
  scan_buckets_kernel<<<1, 256, 0, stream>>>(bcnt, bbase, bfill);
  scatter_kernel<<<nblkE, 256, 0, stream>>>(src, dst, bfill, pairs, E);
  bucket_csr_kernel<<<NB, 256, 0, stream>>>(pairs, bbase, row_ptr, dinv, col, N, E);

  // ---- layer 1: x[N,128] ----
  lin_kernel<128><<<nblkLin, 256, 0, stream>>>(x, WT1, dinv, bufA, N);
  agg_kernel<<<(N+3)/4, 256, 0, stream>>>(bufA, row_ptr, col, dinv, b1, bufB, N);
  // ---- layer 2 ----
  lin_kernel<64><<<nblkLin, 256, 0, stream>>>(bufB, WT2, dinv, bufA, N);
  agg_kernel<<<(N+3)/4, 256, 0, stream>>>(bufA, row_ptr, col, dinv, b2, bufB, N);
  // ---- layer 3 ----
  lin_kernel<64><<<nblkLin, 256, 0, stream>>>(bufB, WT3, dinv, bufA, N);
  agg_kernel<<<(N+3)/4, 256, 0, stream>>>(bufA, row_ptr, col, dinv, b3, bufB, N);
  // ---- FC + log_softmax ----
  final_kernel<<<(N+3)/4, 256, 0, stream>>>(bufB, Wfc, bfc, out, N);
}

// Round 4
// 515.727 us; speedup vs baseline: 1.4541x; 1.4541x over previous
//
#include <hip/hip_runtime.h>
#include <math.h>

// ---------------------------------------------------------------------------
// FraudDetectionGCN: 3x GCNConv(relu) + FC + log_softmax, fp32 throughout.
// R4 changes vs R3:
//  * lin kernels: R2/R3's transposed-W read was pathological (lane stride
//    512B -> 64 cache lines per load -> L1 thrash; more occupancy made it
//    SLOWER). Now W is read in NATURAL [K,64] layout, lane = output feature:
//    one 256B coalesced load per k. h rows are wave-uniform scalar loads
//    (readfirstlane). 8 rows/wave -> 8 FMAs per W element -> VALU-bound.
//    No transpose kernel needed.
//  * final_kernel fused into 3rd agg epilogue (saves 51 MB traffic + launch).
// norm factorization: out[n] = dinv[n]*(sum_{s->n} g[s] + g[n]) + b,
// where g = dinv[:,None] * (h @ W).
// ---------------------------------------------------------------------------

static inline size_t alignup(size_t x){ return (x + 511) & ~size_t(511); }

#define NBUCK 1024          // histogram bins (dst>>7), NB=ceil(N/128) used
#define CHUNK 8192          // edges per block in hist/scatter
#define CCAP  3584          // max edges per bucket (mean ~2046, +30 sigma)

__global__ void zero_kernel(int* __restrict__ p, int n){
  int i = blockIdx.x*256 + threadIdx.x;
  if(i<n) p[i] = 0;
}

// Pass A: global histogram of dst>>7 (LDS-aggregated).
__global__ __launch_bounds__(256) void hist_kernel(const int* __restrict__ dst,
                                                   int* __restrict__ bcnt, int E){
  __shared__ int h[NBUCK];
  int t = threadIdx.x;
  for(int i=t;i<NBUCK;i+=256) h[i]=0;
  __syncthreads();
  int base = blockIdx.x*CHUNK;
  #pragma unroll 4
  for(int i=0;i<CHUNK;i+=256){
    int e = base+i+t;
    if(e<E) atomicAdd(&h[dst[e]>>7], 1);
  }
  __syncthreads();
  for(int i=t;i<NBUCK;i+=256) if(h[i]) atomicAdd(&bcnt[i], h[i]);
}

// Exclusive scan of 1024 bucket counts (single block). bbase = bfill = prefix.
__global__ void scan_buckets_kernel(const int* __restrict__ bcnt, int* __restrict__ bbase,
                                    int* __restrict__ bfill){
  __shared__ int sh[256];
  int t = threadIdx.x;
  int v0=bcnt[4*t], v1=bcnt[4*t+1], v2=bcnt[4*t+2], v3=bcnt[4*t+3];
  int ts = v0+v1+v2+v3;
  sh[t]=ts; __syncthreads();
  for(int off=1; off<256; off<<=1){
    int x=(t>=off)?sh[t-off]:0; __syncthreads();
    sh[t]+=x; __syncthreads();
  }
  int run = sh[t]-ts;
  int i0=4*t;
  bbase[i0+0]=run; bfill[i0+0]=run; run+=v0;
  bbase[i0+1]=run; bfill[i0+1]=run; run+=v1;
  bbase[i0+2]=run; bfill[i0+2]=run; run+=v2;
  bbase[i0+3]=run; bfill[i0+3]=run;
}

// Pass B: scatter packed (local_dst<<17 | src) into bucket regions.
__global__ __launch_bounds__(256) void scatter_kernel(const int* __restrict__ src,
                                                      const int* __restrict__ dst,
                                                      int* __restrict__ bfill,
                                                      int* __restrict__ pairs, int E){
  __shared__ int h[NBUCK];
  __shared__ int base[NBUCK];
  int t = threadIdx.x;
  for(int i=t;i<NBUCK;i+=256) h[i]=0;
  __syncthreads();
  int cbase = blockIdx.x*CHUNK;
  int d[CHUNK/256];
  #pragma unroll
  for(int i=0;i<CHUNK/256;i++){
    int e = cbase+i*256+t;
    d[i] = (e<E) ? dst[e] : -1;
    if(d[i]>=0) atomicAdd(&h[d[i]>>7], 1);
  }
  __syncthreads();
  for(int i=t;i<NBUCK;i+=256) base[i] = h[i] ? atomicAdd(&bfill[i], h[i]) : 0;
  __syncthreads();
  #pragma unroll
  for(int i=0;i<CHUNK/256;i++){
    int e = cbase+i*256+t;
    if(d[i]>=0){
      int b = d[i]>>7;
      int slot = atomicAdd(&base[b], 1);
      pairs[slot] = ((d[i]&127)<<17) | src[e];
    }
  }
}

// Pass C: one block per bucket (128 dst nodes). LDS counting sort ->
// row_ptr, dinv, and fully-sequential col writes.
__global__ __launch_bounds__(256) void bucket_csr_kernel(const int* __restrict__ pairs,
                                                         const int* __restrict__ bbase,
                                                         int* __restrict__ row_ptr,
                                                         float* __restrict__ dinv,
                                                         int* __restrict__ col,
                                                         int N, int E){
  __shared__ int hist[128];
  __shared__ int pref[128];
  __shared__ int fill[128];
  __shared__ int srcs[CCAP];
  int b = blockIdx.x, t = threadIdx.x;
  int s = bbase[b], e = bbase[b+1];
  int cnt = e - s; if(cnt > CCAP) cnt = CCAP;   // unreachable guard
  if(t<128) hist[t]=0;
  __syncthreads();
  int v[CCAP/256];
  #pragma unroll
  for(int i=0;i<CCAP/256;i++){
    int idx = i*256 + t;
    if(idx<cnt){ v[i]=pairs[s+idx]; atomicAdd(&hist[v[i]>>17], 1); }
  }
  __syncthreads();
  if(t<128) pref[t]=hist[t];
  __syncthreads();
  for(int off=1; off<128; off<<=1){
    int x=0;
    if(t<128 && t>=off) x=pref[t-off];
    __syncthreads();
    if(t<128) pref[t]+=x;
    __syncthreads();
  }
  if(t<128){
    int ex = pref[t]-hist[t];                 // exclusive prefix
    fill[t]=ex;
    int node = b*128 + t;
    if(node<N){
      row_ptr[node] = s + ex;
      dinv[node] = rsqrtf((float)(hist[t]+1)); // +1 self loop
    }
  }
  if(b==0 && t==0) row_ptr[N]=E;
  __syncthreads();
  #pragma unroll
  for(int i=0;i<CCAP/256;i++){
    int idx = i*256 + t;
    if(idx<cnt){
      int ld = v[i]>>17;
      int pos = atomicAdd(&fill[ld], 1);
      srcs[pos] = v[i] & 0x1FFFF;
    }
  }
  __syncthreads();
  for(int i=t;i<cnt;i+=256) col[s+i]=srcs[i];
}

// g[n,:] = dinv[n] * (h[n,:K] @ W[K,64]).
// lane = output feature j. W read in natural [K,64] layout: W[k*64+lane] is
// a 256B coalesced wave read (L1-resident, W <= 32KB). h rows wave-uniform
// (readfirstlane -> scalar loads). 8 rows/wave amortize each W element over
// 8 FMAs -> VALU-bound (~10us floor for K=128).
template<int K>
__global__ __launch_bounds__(256) void lin_kernel(const float* __restrict__ h,
                                                  const float* __restrict__ W,
                                                  const float* __restrict__ dinv,
                                                  float* __restrict__ g, int N){
  int t = threadIdx.x, wave = t>>6, lane = t&63;
  int base = (blockIdx.x*4 + wave)*8;
  if(base >= N) return;
  base = __builtin_amdgcn_readfirstlane(base);
  int nr = N - base; if(nr > 8) nr = 8;
  const float* hp = h + (size_t)base*K;
  // clamp row offsets for the (single) tail block
  int off[8];
  #pragma unroll
  for(int r=0;r<8;r++) off[r] = (r<nr ? r : 0)*K;
  float acc[8];
  #pragma unroll
  for(int r=0;r<8;r++) acc[r]=0.f;
  for(int k=0; k<K; k+=4){
    float w0 = W[(k+0)*64 + lane];
    float w1 = W[(k+1)*64 + lane];
    float w2 = W[(k+2)*64 + lane];
    float w3 = W[(k+3)*64 + lane];
    #pragma unroll
    for(int r=0;r<8;r++){
      float4 hv = *(const float4*)&hp[off[r] + k];
      acc[r] += hv.x*w0 + hv.y*w1 + hv.z*w2 + hv.w*w3;
    }
  }
  #pragma unroll
  for(int r=0;r<8;r++){
    if(r<nr) g[(size_t)(base+r)*64 + lane] = dinv[base+r]*acc[r];
  }
}

// h[n,:] = relu(dinv[n]*(g[n,:] + sum_{CSR} g[col,:]) + bias). One wave/node,
// lane == feature; 8-deep unroll for outstanding 256B row gathers.
__global__ __launch_bounds__(256) void agg_kernel(const float* __restrict__ g,
                                                  const int* __restrict__ row_ptr,
                                                  const int* __restrict__ col,
                                                  const float* __restrict__ dinv,
                                                  const float* __restrict__ bias,
                                                  float* __restrict__ h, int N){
  int wave = threadIdx.x>>6, lane = threadIdx.x&63;
  int n = blockIdx.x*4 + wave;
  if(n>=N) return;
  int s = row_ptr[n], e = row_ptr[n+1];
  float acc = g[(size_t)n*64 + lane];          // self loop
  int i = s;
  for(; i+8<=e; i+=8){
    int c0=col[i],c1=col[i+1],c2=col[i+2],c3=col[i+3];
    int c4=col[i+4],c5=col[i+5],c6=col[i+6],c7=col[i+7];
    float x0=g[(size_t)c0*64+lane], x1=g[(size_t)c1*64+lane];
    float x2=g[(size_t)c2*64+lane], x3=g[(size_t)c3*64+lane];
    float x4=g[(size_t)c4*64+lane], x5=g[(size_t)c5*64+lane];
    float x6=g[(size_t)c6*64+lane], x7=g[(size_t)c7*64+lane];
    acc += ((x0+x1)+(x2+x3)) + ((x4+x5)+(x6+x7));
  }
  for(; i<e; ++i) acc += g[(size_t)col[i]*64 + lane];
  float r = dinv[n]*acc + bias[lane];
  h[(size_t)n*64 + lane] = fmaxf(r, 0.0f);
}

// Layer-3 agg with fused FC + log_softmax epilogue: never materializes h3.
__global__ __launch_bounds__(256) void agg_final_kernel(const float* __restrict__ g,
                                                        const int* __restrict__ row_ptr,
                                                        const int* __restrict__ col,
                                                        const float* __restrict__ dinv,
                                                        const float* __restrict__ bias,
                                                        const float* __restrict__ Wfc,
                                                        const float* __restrict__ bfc,
                                                        float* __restrict__ out, int N){
  int wave = threadIdx.x>>6, lane = threadIdx.x&63;
  int n = blockIdx.x*4 + wave;
  if(n>=N) return;
  int s = row_ptr[n], e = row_ptr[n+1];
  float acc = g[(size_t)n*64 + lane];          // self loop
  int i = s;
  for(; i+8<=e; i+=8){
    int c0=col[i],c1=col[i+1],c2=col[i+2],c3=col[i+3];
    int c4=col[i+4],c5=col[i+5],c6=col[i+6],c7=col[i+7];
    float x0=g[(size_t)c0*64+lane], x1=g[(size_t)c1*64+lane];
    float x2=g[(size_t)c2*64+lane], x3=g[(size_t)c3*64+lane];
    float x4=g[(size_t)c4*64+lane], x5=g[(size_t)c5*64+lane];
    float x6=g[(size_t)c6*64+lane], x7=g[(size_t)c7*64+lane];
    acc += ((x0+x1)+(x2+x3)) + ((x4+x5)+(x6+x7));
  }
  for(; i<e; ++i) acc += g[(size_t)col[i]*64 + lane];
  float hv = fmaxf(dinv[n]*acc + bias[lane], 0.0f);   // h3[n][lane]
  float2 w = *(const float2*)&Wfc[lane*2];
  float p0 = hv*w.x, p1 = hv*w.y;
  for(int off=32; off; off>>=1){
    p0 += __shfl_down(p0, off);
    p1 += __shfl_down(p1, off);
  }
  if(lane==0){
    float l0 = p0 + bfc[0], l1 = p1 + bfc[1];
    float m  = fmaxf(l0, l1);
    float lse = m + logf(expf(l0-m) + expf(l1-m));
    out[(size_t)n*2+0] = l0 - lse;
    out[(size_t)n*2+1] = l1 - lse;
  }
}

extern "C" void kernel_launch(void* const* d_in, const int* in_sizes, int n_in,
                              void* d_out, int out_size, void* d_ws, size_t ws_size,
                              hipStream_t stream) {
  (void)n_in; (void)out_size; (void)ws_size;
  const float* x   = (const float*)d_in[0];
  const int*   ei  = (const int*)  d_in[1];
  const float* W1  = (const float*)d_in[2];
  const float* b1  = (const float*)d_in[3];
  const float* W2  = (const float*)d_in[4];
  const float* b2  = (const float*)d_in[5];
  const float* W3  = (const float*)d_in[6];
  const float* b3  = (const float*)d_in[7];
  const float* Wfc = (const float*)d_in[8];
  const float* bfc = (const float*)d_in[9];
  float* out = (float*)d_out;

  const int N = in_sizes[0] / 128;   // 100000
  const int E = in_sizes[1] / 2;     // 1600000
  const int* src = ei;
  const int* dst = ei + E;
  const int NB = (N + 127) / 128;    // 782 buckets

  // ---- workspace carve ----
  char* w = (char*)d_ws;
  int*   bcnt    = (int*)  w; w += alignup((size_t)NBUCK*4);
  int*   bbase   = (int*)  w; w += alignup((size_t)(NBUCK+1)*4);
  int*   bfill   = (int*)  w; w += alignup((size_t)NBUCK*4);
  int*   pairs   = (int*)  w; w += alignup((size_t)E*4);
  int*   row_ptr = (int*)  w; w += alignup((size_t)(N+1)*4);
  float* dinv    = (float*)w; w += alignup((size_t)N*4);
  int*   col     = (int*)  w; w += alignup((size_t)E*4);
  float* bufA    = (float*)w; w += alignup((size_t)N*64*4);
  float* bufB    = (float*)w; w += alignup((size_t)N*64*4);

  const int nblkE   = (E + CHUNK - 1) / CHUNK;   // 196
  const int nblkLin = (N + 31) / 32;             // 3125: 8 rows/wave, 4 waves
  const int nblkAgg = (N + 3) / 4;

  // ---- CSR build ----
  zero_kernel<<<(NBUCK+255)/256, 256, 0, stream>>>(bcnt, NBUCK);
  hist_kernel<<<nblkE, 256, 0, stream>>>(dst, bcnt, E);
  scan_buckets_kernel<<<1, 256, 0, stream>>>(bcnt, bbase, bfill);
  scatter_kernel<<<nblkE, 256, 0, stream>>>(src, dst, bfill, pairs, E);
  bucket_csr_kernel<<<NB, 256, 0, stream>>>(pairs, bbase, row_ptr, dinv, col, N, E);

  // ---- layer 1: x[N,128] ----
  lin_kernel<128><<<nblkLin, 256, 0, stream>>>(x, W1, dinv, bufA, N);
  agg_kernel<<<nblkAgg, 256, 0, stream>>>(bufA, row_ptr, col, dinv, b1, bufB, N);
  // ---- layer 2 ----
  lin_kernel<64><<<nblkLin, 256, 0, stream>>>(bufB, W2, dinv, bufA, N);
  agg_kernel<<<nblkAgg, 256, 0, stream>>>(bufA, row_ptr, col, dinv, b2, bufB, N);
  // ---- layer 3 + FC + log_softmax (fused) ----
  lin_kernel<64><<<nblkLin, 256, 0, stream>>>(bufB, W3, dinv, bufA, N);
  agg_final_kernel<<<nblkAgg, 256, 0, stream>>>(bufA, row_ptr, col, dinv, b3,
                                                Wfc, bfc, out, N);
}